// Round 5
// baseline (427.196 us; speedup 1.0000x reference)
//
#include <hip/hip_runtime.h>
#include <hip/hip_bf16.h>

// Problem constants
#define B_   32
#define C_   128
#define H_   56
#define W_   56
#define KSEL 2
#define E_   8
#define KN_  128
// KS=3, PAD=1

typedef __attribute__((ext_vector_type(8))) short short8;   // 8 x bf16
typedef __attribute__((ext_vector_type(4))) float f32x4;    // MFMA accumulator

static __device__ __forceinline__ ushort f2bf(float f) {
  union { float f; uint u; } v; v.f = f;
  uint u = v.u;
  return (ushort)((u + 0x7fffu + ((u >> 16) & 1u)) >> 16);  // RNE
}

// xh layout: [b][cc(4)][hp(58)][cell(58)][64B] bf16, quad-swizzled:
//   cell holds c = cc*32..+31 as 4 quads of 8 bf16; logical quad q stored at
//   physical position (q + (cell>>1)) & 3. Rows 3712 B (128-aligned), so the
//   bank pattern repeats per row; 64-lane b128 reads spread uniformly over
//   all 8 bank-quad starts (same quality as the old 80B-cell padding) while
//   keeping cells 64B -> 24KB staged batch -> 3 blocks/CU.
#define CELL_US 32
#define ROW_US  1856                 // 58 cells * 32 us = 3712 B
#define PLANE_US (58 * ROW_US)       // one cc plane of one b (215296 B)
#define STAGE_B 24576                // staged bytes per batch (6 rows = 22272, rounded to 24 x 1KB)

// ---------------------------------------------------------------------------
// Kernel 0: fused prep (x -> swizzled bf16 cc-planes) + weight fuse.
// Blocks 0..1855: prep (b = q/58, hp = q%58). Blocks 1856..2367: fuse.
// Independent work co-scheduled: memory-bound prep overlaps VALU-bound fuse.
// ---------------------------------------------------------------------------
__global__ __launch_bounds__(256) void prep_fuse_kernel(
    const float* __restrict__ x,     // [32,128,56,56]
    const float* __restrict__ Ws,    // [E][KN][C][9]
    const float* __restrict__ Wch,   // [E][C][256]
    ushort* __restrict__ xh,
    ushort* __restrict__ Weff) {     // fragment-tiled bf16
  __shared__ __align__(16) char smem[27008];   // max(prep 15232, fuse 26880)
  const int q = blockIdx.x;
  const int tid = threadIdx.x;

  if (q < 1856) {
    // ---------------- prep ----------------
    const int b = q / 58, hp = q - (q / 58) * 58;
    if (hp == 0 || hp == 57) {          // zero halo rows (all 4 cc planes)
      uint4 z = make_uint4(0, 0, 0, 0);
#pragma unroll
      for (int cc = 0; cc < 4; ++cc) {
        ushort* rp = xh + (size_t)(b * 4 + cc) * PLANE_US + (size_t)hp * ROW_US;
        for (int l = tid; l < 232; l += 256) ((uint4*)rp)[l] = z;
      }
      return;
    }
    const int h = hp - 1;
    ushort* sT = (ushort*)smem;         // [w(56)][c(136 pad)]
    const float* xb = x + (size_t)b * C_ * H_ * W_ + h * W_;
#pragma unroll
    for (int it = 0; it < 7; ++it) {
      int i4 = tid + it * 256;          // 0..1791
      int c  = i4 / 14;
      int w4 = (i4 - c * 14) * 4;
      float4 v = *(const float4*)(xb + (size_t)c * (H_ * W_) + w4);
      sT[(w4 + 0) * 136 + c] = f2bf(v.x);
      sT[(w4 + 1) * 136 + c] = f2bf(v.y);
      sT[(w4 + 2) * 136 + c] = f2bf(v.z);
      sT[(w4 + 3) * 136 + c] = f2bf(v.w);
    }
    __syncthreads();
    // 4cc x 58 cells x 4 quads = 928 chunks; quad-swizzled destination
    for (int m = tid; m < 928; m += 256) {
      int cc   = m / 232, rem = m - cc * 232;
      int cell = rem >> 2, qd = rem & 3;
      uint4 v = make_uint4(0, 0, 0, 0);
      if (cell >= 1 && cell <= 56)
        v = *(const uint4*)&sT[(cell - 1) * 136 + cc * 32 + qd * 8];
      int pq = (qd + (cell >> 1)) & 3;
      ushort* rp = xh + (size_t)(b * 4 + cc) * PLANE_US + (size_t)hp * ROW_US;
      *(uint4*)(rp + cell * CELL_US + pq * 8) = v;
    }
  } else {
    // ---------------- fuse (16o x 16c tile per block, 512 blocks) ----------
    const int fid = q - 1856;           // 0..511
    const int e  = fid >> 6;
    const int o0 = ((fid >> 3) & 7) << 4;
    const int c0 = (fid & 7) << 4;
    float* sA = (float*)smem;                    // [16][132]
    float* sB = (float*)(smem + 16 * 132 * 4);   // [32][144]

    // stage sA: 16 o-rows x full K=128 (gate half of Wch)
    for (int m = tid; m < 512; m += 256) {
      int o = m >> 5, kk = (m & 31) * 4;
      float4 v = *(const float4*)(Wch + (size_t)(e * C_ + o0 + o) * 256 + 128 + kk);
      sA[o * 132 + kk + 0] = v.x;
      sA[o * 132 + kk + 1] = v.y;
      sA[o * 132 + kk + 2] = v.z;
      sA[o * 132 + kk + 3] = v.w;
    }

    const int orr = tid >> 4, cl = tid & 15;
    float acc[9];
#pragma unroll
    for (int j = 0; j < 9; ++j) acc[j] = 0.f;

    for (int k0 = 0; k0 < 128; k0 += 32) {
      __syncthreads();
      // stage sB: 32 k-rows x (16c x 9j = 144 contiguous floats)
      for (int m = tid; m < 1152; m += 256) {
        int k = m / 36, f4 = m - k * 36;
        float4 v = *(const float4*)(Ws + ((size_t)(e * KN_ + k0 + k) * C_ + c0) * 9 + f4 * 4);
        *(float4*)&sB[k * 144 + f4 * 4] = v;
      }
      __syncthreads();
      for (int k = 0; k < 32; ++k) {
        float a = sA[orr * 132 + k0 + k];
        const float* bp = &sB[k * 144 + cl * 9];
#pragma unroll
        for (int j = 0; j < 9; ++j) acc[j] += a * bp[j];
      }
    }

    const int o = o0 + orr, c = c0 + cl;
    acc[4] += Wch[(size_t)(e * C_ + o) * 256 + c];
    const int nt   = o >> 4;
    const int ct   = c >> 5;
    const int lane = (((c >> 3) & 3) << 4) | (o & 15);
#pragma unroll
    for (int j = 0; j < 9; ++j) {
      size_t base = ((((size_t)(e * 9 + j) * 8 + nt) * 4 + ct) * 64 + lane) * 8 + (c & 7);
      Weff[base] = f2bf(acc[j]);
    }
  }
}

// ---------------------------------------------------------------------------
// Kernel 1: implicit-GEMM MFMA conv, double-buffered global_load_lds pipeline
// (R3 structure). 24KB batches = exactly 6 DMA loads/wave -> counted
// s_waitcnt vmcnt(6) is a true one-batch-in-flight wait (fixes R3's no-op
// vmcnt(30)). 64B cells + quad-rotation swizzle -> LDS 2x24KB = 48KB ->
// 3 blocks/CU. B fragments direct from L2-resident fragment-tiled Weff.
// ---------------------------------------------------------------------------
#define OSTR 228   // f32 epilogue o-stride (224 + 4 pad)

#define BAR() do { asm volatile("" ::: "memory"); \
                   __builtin_amdgcn_s_barrier();  \
                   asm volatile("" ::: "memory"); } while (0)

__global__ __launch_bounds__(256, 3) void conv_mfma_kernel(
    const ushort* __restrict__ xh,   // swizzled cc-plane layout
    const int* __restrict__ gate,    // [B][KSEL]
    const ushort* __restrict__ Weff, // fragment-tiled bf16
    float* __restrict__ out) {       // [B][KSEL][C][H][W] fp32
  // --- swizzled block mapping: XCD = P%8 gets b in [4*xcd, 4*xcd+4) ---
  const int P   = blockIdx.x;        // 0..895
  const int xcd = P & 7;
  const int s   = P >> 3;            // 0..111
  const int bl  = s / 28;
  const int r1  = s - bl * 28;
  const int g   = r1 / 14;
  const int ht  = r1 - g * 14;       // 0..13
  const int b   = xcd * 4 + bl;
  const int bg  = b * 2 + g;
  const int h0  = ht * 4;
  const int e   = gate[bg];

  const int tid = threadIdx.x;
  const int wv = tid >> 6, lane = tid & 63;
  const int l15 = lane & 15, kq = lane >> 4;
  const int mh = wv >> 1, nh = wv & 1;

  __shared__ __align__(128) char smem[2 * STAGE_B];   // 49152 B
  ushort* bufA = (ushort*)smem;
  ushort* bufB = (ushort*)(smem + STAGE_B);

  f32x4 acc[7][4];
#pragma unroll
  for (int t = 0; t < 7; ++t)
#pragma unroll
    for (int i = 0; i < 4; ++i) acc[t][i] = (f32x4){0.f, 0.f, 0.f, 0.f};

  // per-lane A offsets (ushort units, r-relative) incl. quad swizzle per dx
  int axy[7][3];
#pragma unroll
  for (int t = 0; t < 7; ++t) {
    int p = mh * 112 + t * 16 + l15;   // 0..223
    int r = p / 56;
    int w = p - r * 56;
#pragma unroll
    for (int dx = 0; dx < 3; ++dx) {
      int cell = w + dx;               // 0..57
      axy[t][dx] = r * ROW_US + cell * CELL_US + (((kq + (cell >> 1)) & 3) * 8);
    }
  }

  // stage: rows h0..h0+5 linear = 22272 B, rounded to 24 x 1KB chunks
  // (tail reads past the 6th row into valid adjacent memory; never consumed)
  const char* xbase = (const char*)xh;
#define STAGE(cc, dst) do {                                                   \
    const char* srp = xbase + ((size_t)(b * 4 + (cc)) * PLANE_US              \
                             + (size_t)h0 * ROW_US) * 2 + lane * 16;          \
    char* drp = (char*)(dst);                                                 \
    _Pragma("unroll")                                                         \
    for (int it_ = 0; it_ < 6; ++it_) {                                       \
      int n_ = wv + it_ * 4;           /* exactly 6 loads per wave */         \
      __builtin_amdgcn_global_load_lds(                                       \
          (const __attribute__((address_space(1))) unsigned int*)(srp + n_ * 1024), \
          (__attribute__((address_space(3))) unsigned int*)(drp + n_ * 1024),       \
          16, 0, 0);                                                          \
    }                                                                         \
  } while (0)

  const ushort* wlane = Weff + (size_t)e * (9 * 8 * 4 * 64 * 8)
                             + (size_t)(nh * 4) * (4 * 64 * 8)
                             + (size_t)lane * 8;

#define COMPUTE(sXb, cc) do {                                                 \
    _Pragma("unroll")                                                         \
    for (int dy = 0; dy < 3; ++dy) {                                          \
      _Pragma("unroll")                                                       \
      for (int dx = 0; dx < 3; ++dx) {                                        \
        const int j_ = dy * 3 + dx;                                           \
        short8 bfr[4];                                                        \
        _Pragma("unroll")                                                     \
        for (int i = 0; i < 4; ++i)                                           \
          bfr[i] = *(const short8*)(wlane + (size_t)j_ * (8 * 4 * 64 * 8)     \
                                          + (size_t)i * (4 * 64 * 8)          \
                                          + (size_t)(cc) * (64 * 8));         \
        _Pragma("unroll")                                                     \
        for (int t = 0; t < 7; ++t) {                                         \
          short8 a = *(const short8*)&(sXb)[axy[t][dx] + dy * ROW_US];        \
          _Pragma("unroll")                                                   \
          for (int i = 0; i < 4; ++i)                                         \
            acc[t][i] = __builtin_amdgcn_mfma_f32_16x16x32_bf16(              \
                a, bfr[i], acc[t][i], 0, 0, 0);                               \
        }                                                                     \
      }                                                                       \
    }                                                                         \
  } while (0)

  STAGE(0, bufA);
  STAGE(1, bufB);
  asm volatile("s_waitcnt vmcnt(6)" ::: "memory");   // batch0 landed (counted)
  BAR();
  COMPUTE(bufA, 0);
  BAR();
  STAGE(2, bufA);
  asm volatile("s_waitcnt vmcnt(6)" ::: "memory");   // batch1 landed
  BAR();
  COMPUTE(bufB, 1);
  BAR();
  STAGE(3, bufB);
  asm volatile("s_waitcnt vmcnt(6)" ::: "memory");   // batch2 landed
  BAR();
  COMPUTE(bufA, 2);
  asm volatile("s_waitcnt vmcnt(0)" ::: "memory");   // batch3 landed
  BAR();
  COMPUTE(bufB, 3);
  BAR();   // all LDS reads done before sO overwrite

  // -------- LDS-transposed epilogue: 4 groups of 32 o (sO spans both bufs) --
  float* sO = (float*)smem;
  for (int gq = 0; gq < 4; ++gq) {
    if (nh == (gq >> 1)) {
      const int gg = gq & 1;
#pragma unroll
      for (int ii = 0; ii < 2; ++ii) {
        const int i = gg * 2 + ii;
#pragma unroll
        for (int t = 0; t < 7; ++t) {
          int p0 = mh * 112 + t * 16 + kq * 4;
          int r  = p0 / 56;
          int w0 = p0 - r * 56;
          *(float4*)&sO[(ii * 16 + l15) * OSTR + r * 56 + w0] =
              make_float4(acc[t][i][0], acc[t][i][1], acc[t][i][2], acc[t][i][3]);
        }
      }
    }
    __syncthreads();   // staged data visible
    {
      float* ob = out + ((size_t)bg * C_ + 32 * gq) * (H_ * W_) + (size_t)h0 * W_;
#pragma unroll
      for (int k = 0; k < 7; ++k) {
        int idx = k * 256 + tid;        // 0..1791
        int ol  = idx / 56;
        int pos = idx - ol * 56;
        float4 v = *(const float4*)&sO[ol * OSTR + pos * 4];
        *(float4*)(ob + (size_t)ol * (H_ * W_) + pos * 4) = v;
      }
    }
    __syncthreads();   // write-out reads done before next group staging
  }
}

extern "C" void kernel_launch(void* const* d_in, const int* in_sizes, int n_in,
                              void* d_out, int out_size, void* d_ws, size_t ws_size,
                              hipStream_t stream) {
  const float* x    = (const float*)d_in[0];   // [32,128,56,56]
  const int*   gate = (const int*)d_in[1];     // [32,2]
  const float* Ws   = (const float*)d_in[2];   // [8,128,128,3,3]
  const float* Wch  = (const float*)d_in[3];   // [8,128,256,1,1]
  float* out = (float*)d_out;                  // [32,2,128,56,56]

  ushort* xh   = (ushort*)d_ws;                       // 32*4 planes = 27.56 MB
  ushort* Weff = xh + (size_t)(32 * 4) * PLANE_US;    // 2.36 MB

  dim3 g0(1856 + 512);
  prep_fuse_kernel<<<g0, 256, 0, stream>>>(x, Ws, Wch, xh, Weff);

  dim3 g2(896);
  conv_mfma_kernel<<<g2, 256, 0, stream>>>(xh, gate, Weff, out);
}

// Round 6
// 232.320 us; speedup vs baseline: 1.8388x; 1.8388x over previous
//
#include <hip/hip_runtime.h>
#include <hip/hip_bf16.h>

// Problem constants
#define B_   32
#define C_   128
#define H_   56
#define W_   56
#define KSEL 2
#define E_   8
#define KN_  128
// KS=3, PAD=1

typedef __attribute__((ext_vector_type(8))) short short8;   // 8 x bf16
typedef __attribute__((ext_vector_type(4))) float f32x4;    // MFMA accumulator

static __device__ __forceinline__ ushort f2bf(float f) {
  union { float f; uint u; } v; v.f = f;
  uint u = v.u;
  return (ushort)((u + 0x7fffu + ((u >> 16) & 1u)) >> 16);  // RNE
}

// xh layout (R3-proven, conv-ready LDS image): [b][cc(4)][hp(58)][cell(64)][40 us]
//   cell w' holds c = cc*32 .. cc*32+31 in its first 32 ushorts, 8 pad.
//   cells 58..63 and all halo cells/rows are zero. Row = 5120 B.
#define CELL_US 40
#define ROW_US  2560          // 64 cells * 40
#define ROW_B   5120
#define REG_B   30720         // 6 rows staged per (cc, h0)

// ---------------------------------------------------------------------------
// Kernel 0: FUSED prep (x -> padded bf16 cc-planes) + weight fuse.
// Blocks 0..1855: prep (b = q/58, hp = q%58).
// Blocks 1856..2111: fuse, 32o x 16c tile each (8e x 4ot x 8ct = 256).
// Independent work co-scheduled: memory-bound prep overlaps VALU-bound fuse.
// LDS = max(prep 15232, fuse 35456) = 35456 B.
// ---------------------------------------------------------------------------
__global__ __launch_bounds__(256) void prep_fuse_kernel(
    const float* __restrict__ x,     // [32,128,56,56]
    const float* __restrict__ Ws,    // [E][KN][C][9]
    const float* __restrict__ Wch,   // [E][C][256]
    ushort* __restrict__ xh,
    ushort* __restrict__ Weff) {     // fragment-tiled bf16
  __shared__ __align__(16) char smem[35456];
  const int q = blockIdx.x;
  const int tid = threadIdx.x;

  if (q < 1856) {
    // ---------------- prep (R3 layout: 40-ushort padded cells) -------------
    const int b = q / 58, hp = q - (q / 58) * 58;
    if (hp == 0 || hp == 57) {          // zero halo rows (all 4 cc planes)
      uint4 z = make_uint4(0, 0, 0, 0);
#pragma unroll
      for (int cc = 0; cc < 4; ++cc) {
        ushort* rp = xh + ((size_t)(b * 4 + cc) * 58 + hp) * ROW_US;
        for (int l = tid; l < 320; l += 256) ((uint4*)rp)[l] = z;
      }
      return;
    }
    const int h = hp - 1;
    ushort* sT = (ushort*)smem;         // [w(56)][c(136 pad)]
    const float* xb = x + (size_t)b * C_ * H_ * W_ + h * W_;
#pragma unroll
    for (int it = 0; it < 7; ++it) {
      int i4 = tid + it * 256;          // 0..1791
      int c  = i4 / 14;
      int w4 = (i4 - c * 14) * 4;
      float4 v = *(const float4*)(xb + (size_t)c * (H_ * W_) + w4);
      sT[(w4 + 0) * 136 + c] = f2bf(v.x);
      sT[(w4 + 1) * 136 + c] = f2bf(v.y);
      sT[(w4 + 2) * 136 + c] = f2bf(v.z);
      sT[(w4 + 3) * 136 + c] = f2bf(v.w);
    }
    __syncthreads();
    // 4cc x 64 cells x 5 uint4 = 1280 chunks, contiguous per row
    for (int m = tid; m < 1280; m += 256) {
      int cc   = m / 320, rem = m - cc * 320;
      int cell = rem / 5, sub = rem - cell * 5;
      uint4 v = make_uint4(0, 0, 0, 0);
      if (sub < 4 && cell >= 1 && cell <= 56)
        v = *(const uint4*)&sT[(cell - 1) * 136 + cc * 32 + sub * 8];
      ushort* rp = xh + ((size_t)(b * 4 + cc) * 58 + hp) * ROW_US;
      *(uint4*)(rp + cell * CELL_US + sub * 8) = v;
    }
  } else {
    // ---------------- fuse: 32o x 16c tile, fp32 tiled GEMM ----------------
    const int fid = q - 1856;           // 0..255
    const int e  = fid >> 5;
    const int o0 = ((fid >> 3) & 3) * 32;
    const int c0 = (fid & 7) * 16;
    float* sA = (float*)smem;                    // [32][129]
    float* sB = (float*)(smem + 32 * 129 * 4);   // [32][148]

    // stage sA: 32 o-rows x full K=128 (gate half of Wch)
    for (int m = tid; m < 1024; m += 256) {
      int o = m >> 5, kk = (m & 31) * 4;
      float4 v = *(const float4*)(Wch + (size_t)(e * C_ + o0 + o) * 256 + 128 + kk);
      sA[o * 129 + kk + 0] = v.x;
      sA[o * 129 + kk + 1] = v.y;
      sA[o * 129 + kk + 2] = v.z;
      sA[o * 129 + kk + 3] = v.w;
    }

    const int o  = tid >> 3;            // 0..31
    const int cp = (tid & 7) * 2;       // 0..14 (2 c's per thread)
    float acc[9][2];
#pragma unroll
    for (int j = 0; j < 9; ++j) { acc[j][0] = 0.f; acc[j][1] = 0.f; }

    for (int k0 = 0; k0 < 128; k0 += 32) {
      __syncthreads();
      // stage sB: 32 k-rows x (16c x 9j = 144 contiguous floats), row pad 148
      for (int m = tid; m < 1152; m += 256) {
        int k = m / 36, f4 = m - k * 36;
        float4 v = *(const float4*)(Ws + ((size_t)(e * KN_ + k0 + k) * C_ + c0) * 9 + f4 * 4);
        *(float4*)&sB[k * 148 + f4 * 4] = v;
      }
      __syncthreads();
      for (int k = 0; k < 32; ++k) {
        float a = sA[o * 129 + k0 + k];
#pragma unroll
        for (int c2 = 0; c2 < 2; ++c2) {
          const float* bp = &sB[k * 148 + (cp + c2) * 9];
#pragma unroll
          for (int j = 0; j < 9; ++j) acc[j][c2] += a * bp[j];
        }
      }
    }

    const int og  = o0 + o;
    const int cg0 = c0 + cp;
#pragma unroll
    for (int c2 = 0; c2 < 2; ++c2)
      acc[4][c2] += Wch[(size_t)(e * C_ + og) * 256 + cg0 + c2];

    // fragment-tiled store: Weff[e][j][nt(8)][ct(4)][lane(64)][8]
    const int nt   = og >> 4;
    const int ct5  = cg0 >> 5;
    const int lane = (((cg0 >> 3) & 3) << 4) | (og & 15);
#pragma unroll
    for (int j = 0; j < 9; ++j) {
      uint w = (uint)f2bf(acc[j][0]) | ((uint)f2bf(acc[j][1]) << 16);
      size_t base = ((((size_t)(e * 9 + j) * 8 + nt) * 4 + ct5) * 64 + lane) * 8
                    + (cg0 & 7);
      *(uint*)(Weff + base) = w;
    }
  }
}

// ---------------------------------------------------------------------------
// Kernel 1: implicit-GEMM MFMA conv (EXACT R3 structure, proven 74.5 us).
// Double-buffered global_load_lds pipeline; B fragments direct from
// L2-resident fragment-tiled Weff; LDS-transposed store epilogue.
// launch_bounds(256,2): VGPR budget 256/wave -> no spills (R4/R5 lesson:
// (256,3) caps at ~170 < the ~196 this kernel needs -> scratch spill storm,
// +230 MB sym. FETCH/WRITE). 2 blocks/CU.
// ---------------------------------------------------------------------------
#define OSTR 228   // f32 epilogue o-stride (224 + 4 pad)

#define BAR() do { asm volatile("" ::: "memory"); \
                   __builtin_amdgcn_s_barrier();  \
                   asm volatile("" ::: "memory"); } while (0)

__global__ __launch_bounds__(256, 2) void conv_mfma_kernel(
    const ushort* __restrict__ xh,   // padded cc-plane layout, see prep
    const int* __restrict__ gate,    // [B][KSEL]
    const ushort* __restrict__ Weff, // fragment-tiled bf16
    float* __restrict__ out) {       // [B][KSEL][C][H][W] fp32
  // --- swizzled block mapping: XCD = P%8 gets b in [4*xcd, 4*xcd+4) ---
  const int P   = blockIdx.x;        // 0..895
  const int xcd = P & 7;
  const int s   = P >> 3;            // 0..111
  const int bl  = s / 28;
  const int r1  = s - bl * 28;
  const int g   = r1 / 14;
  const int ht  = r1 - g * 14;       // 0..13
  const int b   = xcd * 4 + bl;
  const int bg  = b * 2 + g;
  const int h0  = ht * 4;
  const int e   = gate[bg];

  const int tid = threadIdx.x;
  const int wv = tid >> 6, lane = tid & 63;
  const int l15 = lane & 15, kq = lane >> 4;
  const int mh = wv >> 1, nh = wv & 1;

  __shared__ __align__(128) char smem[2 * REG_B];   // 61440 B
  ushort* bufA = (ushort*)smem;
  ushort* bufB = (ushort*)(smem + REG_B);

  f32x4 acc[7][4];
#pragma unroll
  for (int t = 0; t < 7; ++t)
#pragma unroll
    for (int i = 0; i < 4; ++i) acc[t][i] = (f32x4){0.f, 0.f, 0.f, 0.f};

  int addr0[7];
#pragma unroll
  for (int t = 0; t < 7; ++t) {
    int p = mh * 112 + t * 16 + l15;   // 0..223
    int r = p / 56;
    int w = p - r * 56;
    addr0[t] = (r * 64 + w) * CELL_US + kq * 8;   // ushort index
  }

  // stage: 6 rows x 5120 B = 30 x 1024 B DMA chunks, waves round-robin
  const char* xbase = (const char*)xh;
#define STAGE(cc, dst) do {                                                   \
    const char* srp = xbase + ((size_t)((b * 4 + (cc)) * 58 + h0)) * ROW_B    \
                            + lane * 16;                                      \
    char* drp = (char*)(dst);                                                 \
    _Pragma("unroll")                                                         \
    for (int it_ = 0; it_ < 8; ++it_) {                                       \
      int n_ = wv + it_ * 4;                                                  \
      if (n_ < 30)                                                            \
        __builtin_amdgcn_global_load_lds(                                     \
            (const __attribute__((address_space(1))) unsigned int*)(srp + n_ * 1024), \
            (__attribute__((address_space(3))) unsigned int*)(drp + n_ * 1024),       \
            16, 0, 0);                                                        \
    }                                                                         \
  } while (0)

  const ushort* wlane = Weff + (size_t)e * (9 * 8 * 4 * 64 * 8)
                             + (size_t)(nh * 4) * (4 * 64 * 8)
                             + (size_t)lane * 8;

#define COMPUTE(sXb, cc) do {                                                 \
    _Pragma("unroll")                                                         \
    for (int dy = 0; dy < 3; ++dy) {                                          \
      _Pragma("unroll")                                                       \
      for (int dx = 0; dx < 3; ++dx) {                                        \
        const int j_ = dy * 3 + dx;                                           \
        short8 bfr[4];                                                        \
        _Pragma("unroll")                                                     \
        for (int i = 0; i < 4; ++i)                                           \
          bfr[i] = *(const short8*)(wlane + (size_t)j_ * (8 * 4 * 64 * 8)     \
                                          + (size_t)i * (4 * 64 * 8)          \
                                          + (size_t)(cc) * (64 * 8));         \
        const int ao = (dy * 64 + dx) * CELL_US;                              \
        _Pragma("unroll")                                                     \
        for (int t = 0; t < 7; ++t) {                                         \
          short8 a = *(const short8*)&(sXb)[addr0[t] + ao];                   \
          _Pragma("unroll")                                                   \
          for (int i = 0; i < 4; ++i)                                         \
            acc[t][i] = __builtin_amdgcn_mfma_f32_16x16x32_bf16(              \
                a, bfr[i], acc[t][i], 0, 0, 0);                               \
        }                                                                     \
      }                                                                       \
    }                                                                         \
  } while (0)

  STAGE(0, bufA);
  STAGE(1, bufB);
  asm volatile("s_waitcnt vmcnt(30)" ::: "memory");   // batch0 landed
  BAR();
  COMPUTE(bufA, 0);
  BAR();
  STAGE(2, bufA);
  asm volatile("s_waitcnt vmcnt(30)" ::: "memory");   // batch1 landed
  BAR();
  COMPUTE(bufB, 1);
  BAR();
  STAGE(3, bufB);
  asm volatile("s_waitcnt vmcnt(30)" ::: "memory");   // batch2 landed
  BAR();
  COMPUTE(bufA, 2);
  BAR();
  asm volatile("s_waitcnt vmcnt(0)" ::: "memory");    // batch3 landed
  BAR();
  COMPUTE(bufB, 3);

  // -------- LDS-transposed epilogue (sO = bufA; last compute read bufB) ----
  float* sO = (float*)bufA;
  for (int gq = 0; gq < 4; ++gq) {
    if (nh == (gq >> 1)) {
      const int gg = gq & 1;
#pragma unroll
      for (int ii = 0; ii < 2; ++ii) {
        const int i = gg * 2 + ii;
#pragma unroll
        for (int t = 0; t < 7; ++t) {
          int p0 = mh * 112 + t * 16 + kq * 4;
          int r  = p0 / 56;
          int w0 = p0 - r * 56;
          *(float4*)&sO[(ii * 16 + l15) * OSTR + r * 56 + w0] =
              make_float4(acc[t][i][0], acc[t][i][1], acc[t][i][2], acc[t][i][3]);
        }
      }
    }
    __syncthreads();   // staged data visible
    {
      float* ob = out + ((size_t)bg * C_ + 32 * gq) * (H_ * W_) + (size_t)h0 * W_;
#pragma unroll
      for (int k = 0; k < 7; ++k) {
        int idx = k * 256 + tid;        // 0..1791
        int ol  = idx / 56;
        int pos = idx - ol * 56;
        float4 v = *(const float4*)&sO[ol * OSTR + pos * 4];
        *(float4*)(ob + (size_t)ol * (H_ * W_) + pos * 4) = v;
      }
    }
    __syncthreads();   // write-out reads done before next group staging
  }
}

extern "C" void kernel_launch(void* const* d_in, const int* in_sizes, int n_in,
                              void* d_out, int out_size, void* d_ws, size_t ws_size,
                              hipStream_t stream) {
  const float* x    = (const float*)d_in[0];   // [32,128,56,56]
  const int*   gate = (const int*)d_in[1];     // [32,2]
  const float* Ws   = (const float*)d_in[2];   // [8,128,128,3,3]
  const float* Wch  = (const float*)d_in[3];   // [8,128,256,1,1]
  float* out = (float*)d_out;                  // [32,2,128,56,56]

  ushort* xh   = (ushort*)d_ws;                       // 32*4*58*2560 us = 38.0 MB
  ushort* Weff = xh + (size_t)32 * 4 * 58 * ROW_US;   // 2.36 MB

  dim3 g0(1856 + 256);
  prep_fuse_kernel<<<g0, 256, 0, stream>>>(x, Ws, Wch, xh, Weff);

  dim3 g2(896);
  conv_mfma_kernel<<<g2, 256, 0, stream>>>(xh, gate, Weff, out);
}